// Round 16
// baseline (182.218 us; speedup 1.0000x reference)
//
#include <hip/hip_runtime.h>

// MHSA fwd MFMA bf16: B=8, N=1024, D=1024, H=16, DK=64. fp32 in/out, bf16 compute.
// Round 16: GEMMs -> m97-style high-occupancy structure: 128x128 tile, BK=32,
// 256 thr / 4 waves (2Mx2N, 64x64 per wave), 2-buf 32KB LDS, one
// __syncthreads per K-tile (stage-after-barrier), ~3 blocks/CU TLP.
// Attention (R15 swapped-QK^T) and prep unchanged.

typedef __attribute__((ext_vector_type(8))) short bf16x8;
typedef __attribute__((ext_vector_type(4))) float f32x4;

#define GLOAD_LDS16(gp, lp)                                                              \
  __builtin_amdgcn_global_load_lds((const __attribute__((address_space(1))) void*)(gp),  \
                                   (__attribute__((address_space(3))) void*)(lp), 16, 0, 0)

__device__ __forceinline__ unsigned short f2bf(float f) {
  unsigned int u = __float_as_uint(f);
  u += 0x7fffu + ((u >> 16) & 1u);          // RNE
  return (unsigned short)(u >> 16);
}

// ---------------------------------------------------------------------------
// Fused pre-pass: blocks [0,2048) cast x->bf16; [2048,5120) transpose W_qkv;
// [5120,6144) transpose W_o.
// ---------------------------------------------------------------------------
__global__ __launch_bounds__(256) void prep_fused(
    const float* __restrict__ x, unsigned short* __restrict__ x_bf,
    const float* __restrict__ W_qkv, unsigned short* __restrict__ wqkv_t,
    const float* __restrict__ W_o, unsigned short* __restrict__ wo_t) {
  const int b = blockIdx.x;
  if (b < 2048) {
    const int n4 = 8388608 / 4;
    for (int i = b * 256 + threadIdx.x; i < n4; i += 2048 * 256) {
      float4 v = reinterpret_cast<const float4*>(x)[i];
      ushort4 o;
      o.x = f2bf(v.x); o.y = f2bf(v.y); o.z = f2bf(v.z); o.w = f2bf(v.w);
      reinterpret_cast<ushort4*>(x_bf)[i] = o;
    }
  } else {
    __shared__ float tile[32][33];
    const float* W;
    unsigned short* Wt;
    int R = 1024, C, bx, by;
    if (b < 5120) {
      W = W_qkv; Wt = wqkv_t; C = 3072;
      int bb = b - 2048; bx = bb % 96; by = bb / 96;
    } else {
      W = W_o; Wt = wo_t; C = 1024;
      int bb = b - 5120; bx = bb & 31; by = bb >> 5;
    }
    const int tx = threadIdx.x & 31, ty = threadIdx.x >> 5;
    const int c0 = bx * 32, r0 = by * 32;
    #pragma unroll
    for (int i = 0; i < 4; i++) {
      int r = r0 + ty + i * 8;
      tile[ty + i * 8][tx] = W[(size_t)r * C + c0 + tx];
    }
    __syncthreads();
    #pragma unroll
    for (int i = 0; i < 4; i++) {
      int c = c0 + ty + i * 8;
      Wt[(size_t)c * R + r0 + tx] = f2bf(tile[tx][ty + i * 8]);
    }
  }
}

// ---------------------------------------------------------------------------
// GEMM m97-style: 128x128 tile, BK=32, 256 thr = 4 waves (2M x 2N, 64x64 per
// wave, 4x4 16x16 frags). 2-buf LDS (32KB total) -> ~3 blocks/CU. Per K-tile:
// __syncthreads (drains prefetch) -> stage kt+1 -> 8 ds_read_b128 -> 16 MFMA.
// Cross-block TLP hides the barrier drain (m114 mechanism).
// MODE 0: qkv scatter (Q pre-scaled 0.125, V transposed per head). MODE 1: f32.
// ---------------------------------------------------------------------------
template <int MODE>
__global__ __launch_bounds__(256) void gemm97(
    const unsigned short* __restrict__ A, const unsigned short* __restrict__ Bt,
    const float* __restrict__ bias, unsigned short* __restrict__ qkv_out,
    float* __restrict__ Cout) {
  __shared__ __align__(16) unsigned short As[2][128 * 32];   // 16 KB
  __shared__ __align__(16) unsigned short Bs[2][128 * 32];   // 16 KB
  const int t = threadIdx.x;
  const int lane = t & 63, wid = t >> 6;
  const int lr = lane & 15, g = lane >> 4;
  const int wm = wid >> 1, wn = wid & 1;    // 2M x 2N

  // XCD-aware swizzle (nwg divisible by 8: 1536 / 512)
  const int nwg = gridDim.x * gridDim.y;
  const int id = blockIdx.x + gridDim.x * blockIdx.y;
  const int sw = (id & 7) * (nwg >> 3) + (id >> 3);
  const int bx = sw % gridDim.x, by = sw / gridDim.x;
  const int row0 = by * 128, col0 = bx * 128;

  const int srow = t >> 2;                       // 0..63 (64B rows: 32 bf16)
  const int sch  = (t & 3) ^ ((srow >> 1) & 3);  // source pre-swizzle chunk

  auto stA = [&](int buf, int kt, int j) {   // j=0..1: rows j*64..j*64+63
    GLOAD_LDS16(A + (size_t)(row0 + j * 64 + srow) * 1024 + kt * 32 + sch * 8,
                (char*)&As[buf][0] + j * 4096 + t * 16);
  };
  auto stB = [&](int buf, int kt, int j) {
    GLOAD_LDS16(Bt + (size_t)(col0 + j * 64 + srow) * 1024 + kt * 32 + sch * 8,
                (char*)&Bs[buf][0] + j * 4096 + t * 16);
  };
  auto rdA = [&](int buf, int m) -> bf16x8 {
    int r = wm * 64 + m * 16 + lr;
    return *(const bf16x8*)((const char*)&As[buf][0] + r * 64 +
                            ((g ^ ((r >> 1) & 3)) * 16));
  };
  auto rdB = [&](int buf, int n) -> bf16x8 {
    int r = wn * 64 + n * 16 + lr;
    return *(const bf16x8*)((const char*)&Bs[buf][0] + r * 64 +
                            ((g ^ ((r >> 1) & 3)) * 16));
  };

  f32x4 acc[4][4] = {};

  stA(0, 0, 0); stA(0, 0, 1); stB(0, 0, 0); stB(0, 0, 1);

  for (int kt = 0; kt < 32; kt++) {
    const int buf = kt & 1;
    __syncthreads();   // vmcnt(0)+barrier: tile kt landed; buf^1 readers done
    if (kt + 1 < 32) {
      stA(buf ^ 1, kt + 1, 0); stA(buf ^ 1, kt + 1, 1);
      stB(buf ^ 1, kt + 1, 0); stB(buf ^ 1, kt + 1, 1);
    }
    bf16x8 a[4], b[4];
    #pragma unroll
    for (int m = 0; m < 4; m++) a[m] = rdA(buf, m);
    #pragma unroll
    for (int n = 0; n < 4; n++) b[n] = rdB(buf, n);
    #pragma unroll
    for (int m = 0; m < 4; m++)
      #pragma unroll
      for (int n = 0; n < 4; n++)
        acc[m][n] = __builtin_amdgcn_mfma_f32_16x16x32_bf16(a[m], b[n], acc[m][n], 0, 0, 0);
  }

  // ---------------- epilogue ----------------
  if (MODE == 0) {
    const int which = col0 >> 10;   // block-uniform (1024 % 128 == 0)
    if (which == 2) {
      #pragma unroll
      for (int m = 0; m < 4; m++) {
        int row = row0 + wm * 64 + m * 16 + g * 4;
        int bb = row >> 10, nn = row & 1023;
        #pragma unroll
        for (int n = 0; n < 4; n++) {
          int col = col0 + wn * 64 + n * 16 + lr;
          int cc = col & 1023;
          int h = cc >> 6, dk = cc & 63;
          float bv = bias[col];
          ushort4 w;
          w.x = f2bf(acc[m][n][0] + bv);
          w.y = f2bf(acc[m][n][1] + bv);
          w.z = f2bf(acc[m][n][2] + bv);
          w.w = f2bf(acc[m][n][3] + bv);
          size_t idx = ((size_t)2 << 23) + (((size_t)(bb * 16 + h)) << 16) +
                       (size_t)dk * 1024 + nn;
          *(ushort4*)(qkv_out + idx) = w;
        }
      }
    } else {
      #pragma unroll
      for (int m = 0; m < 4; m++) {
        #pragma unroll
        for (int n = 0; n < 4; n++) {
          int col = col0 + wn * 64 + n * 16 + lr;
          int cc = col & 1023;
          int h = cc >> 6, dk = cc & 63;
          #pragma unroll
          for (int r = 0; r < 4; r++) {
            int row = row0 + wm * 64 + m * 16 + g * 4 + r;
            int bb = row >> 10, nn = row & 1023;
            float v = acc[m][n][r] + bias[col];
            if (which == 0) v *= 0.125f;   // fold 1/sqrt(dk) into Q
            size_t idx = ((size_t)which << 23) +
                         (((size_t)((bb * 16 + h) * 1024 + nn)) << 6) + dk;
            qkv_out[idx] = f2bf(v);
          }
        }
      }
    }
  } else {
    #pragma unroll
    for (int m = 0; m < 4; m++) {
      #pragma unroll
      for (int n = 0; n < 4; n++) {
        int col = col0 + wn * 64 + n * 16 + lr;
        #pragma unroll
        for (int r = 0; r < 4; r++) {
          int row = row0 + wm * 64 + m * 16 + g * 4 + r;
          Cout[(size_t)row * 1024 + col] = acc[m][n][r] + bias[col];
        }
      }
    }
  }
}

// ---------------------------------------------------------------------------
// Attention v7 (R15): 8 waves, QBLK=128, KVBLK=64, dbuf K+V via swizzled
// global_load_lds. Swapped QK^T (s4 = mfma(K,Q)): lane holds P[q=lr][4
// consecutive k] -> packed ds_write_b64; den scalar per lane, reduced at end.
// ---------------------------------------------------------------------------
__global__ __launch_bounds__(512) void attn_mfma(
    const unsigned short* __restrict__ qkv, unsigned short* __restrict__ attn_out) {
  __shared__ __align__(16) unsigned short K_lds[2][64 * 64];   // [k][d] swz
  __shared__ __align__(16) unsigned short V_lds[2][64 * 64];   // [d][k] swz
  __shared__ __align__(16) unsigned short P_lds[128 * 64];     // [q][k] swz

  const int bid = ((blockIdx.x & 7) << 7) + (blockIdx.x >> 3);
  const int bh = bid >> 3, qt = bid & 7;
  const unsigned short* Qp = qkv + ((size_t)bh << 16);
  const unsigned short* Kp = qkv + (1u << 23) + ((size_t)bh << 16);
  const unsigned short* Vt = qkv + (2u << 23) + ((size_t)bh << 16);  // [dk][n]

  const int t = threadIdx.x;
  const int lane = t & 63, wid = t >> 6;
  const int lr = lane & 15, g = lane >> 4;

  bf16x8 qf[2];
  {
    int qrow = qt * 128 + wid * 16 + lr;
    qf[0] = *(const bf16x8*)(Qp + (size_t)qrow * 64 + g * 8);
    qf[1] = *(const bf16x8*)(Qp + (size_t)qrow * 64 + 32 + g * 8);
  }

  const int srow = t >> 3;
  const int sch  = (t & 7) ^ (srow & 7);
  const int so   = t * 16;

  auto stage = [&](int buf, int kt) {
    GLOAD_LDS16(Kp + (size_t)(kt * 64 + srow) * 64 + sch * 8, (char*)&K_lds[buf][0] + so);
    GLOAD_LDS16(Vt + (size_t)srow * 1024 + kt * 64 + sch * 8, (char*)&V_lds[buf][0] + so);
  };

  f32x4 o_acc[4] = {};
  float den_l = 0.f;                 // per-lane scalar: q=lr, k-subset (g,ks)
  const int qrow_w = wid * 16 + lr;  // P row this lane writes

  stage(0, 0);
  __syncthreads();
  int buf = 0;
  for (int kt = 0; kt < 16; kt++) {
    if (kt + 1 < 16) stage(buf ^ 1, kt + 1);

    // swapped QK^T: D[k][q] -> lane holds q=lr, k=ks*16+g*4+r
    f32x4 s4[4] = {};
    __builtin_amdgcn_s_setprio(1);
    #pragma unroll
    for (int ks = 0; ks < 4; ks++) {
      int krow = ks * 16 + lr;
      #pragma unroll
      for (int c = 0; c < 2; c++) {
        bf16x8 kf = *(const bf16x8*)((char*)&K_lds[buf][0] + krow * 128 +
                                     ((c * 64 + g * 16) ^ ((krow & 7) << 4)));
        s4[ks] = __builtin_amdgcn_mfma_f32_16x16x32_bf16(kf, qf[c], s4[ks], 0, 0, 0);
      }
    }
    __builtin_amdgcn_s_setprio(0);

    // exp + packed P write: 4 consecutive k per lane -> one b64 per ks
    #pragma unroll
    for (int ks = 0; ks < 4; ks++) {
      float e0 = __expf(s4[ks][0]);
      float e1 = __expf(s4[ks][1]);
      float e2 = __expf(s4[ks][2]);
      float e3 = __expf(s4[ks][3]);
      den_l += (e0 + e1) + (e2 + e3);
      unsigned int lo = (unsigned int)f2bf(e0) | ((unsigned int)f2bf(e1) << 16);
      unsigned int hi = (unsigned int)f2bf(e2) | ((unsigned int)f2bf(e3) << 16);
      int k0 = ks * 16 + g * 4;
      *(uint2*)((char*)P_lds + qrow_w * 128 +
                ((k0 * 2) ^ ((qrow_w & 7) << 4))) = make_uint2(lo, hi);
    }

    bf16x8 pa[2];
    {
      int q = wid * 16 + lr;
      #pragma unroll
      for (int c = 0; c < 2; c++)
        pa[c] = *(const bf16x8*)((char*)P_lds + q * 128 +
                                 ((c * 64 + g * 16) ^ ((q & 7) << 4)));
    }
    __builtin_amdgcn_s_setprio(1);
    #pragma unroll
    for (int ds_ = 0; ds_ < 4; ds_++) {
      int drow = ds_ * 16 + lr;
      #pragma unroll
      for (int c = 0; c < 2; c++) {
        bf16x8 vf = *(const bf16x8*)((char*)&V_lds[buf][0] + drow * 128 +
                                     ((c * 64 + g * 16) ^ ((drow & 7) << 4)));
        o_acc[ds_] = __builtin_amdgcn_mfma_f32_16x16x32_bf16(pa[c], vf, o_acc[ds_], 0, 0, 0);
      }
    }
    __builtin_amdgcn_s_setprio(0);
    __syncthreads();
    buf ^= 1;
  }

  // den: reduce across g-groups; lane l then holds den(q=l&15)
  den_l += __shfl_xor(den_l, 16, 64);
  den_l += __shfl_xor(den_l, 32, 64);
  float den_r[4];
  #pragma unroll
  for (int r = 0; r < 4; r++) den_r[r] = __shfl(den_l, g * 4 + r, 64);

  const int bb = bh >> 4, h = bh & 15;
  #pragma unroll
  for (int ds_ = 0; ds_ < 4; ds_++) {
    #pragma unroll
    for (int r = 0; r < 4; r++) {
      int q = qt * 128 + wid * 16 + g * 4 + r;
      int d = h * 64 + ds_ * 16 + lr;
      attn_out[((size_t)(bb * 1024 + q)) * 1024 + d] = f2bf(o_acc[ds_][r] / den_r[r]);
    }
  }
}

// ---------------------------------------------------------------------------
extern "C" void kernel_launch(void* const* d_in, const int* in_sizes, int n_in,
                              void* d_out, int out_size, void* d_ws, size_t ws_size,
                              hipStream_t stream) {
  const float* x     = (const float*)d_in[0];
  const float* W_qkv = (const float*)d_in[1];
  const float* b_qkv = (const float*)d_in[2];
  const float* W_o   = (const float*)d_in[3];
  const float* b_o   = (const float*)d_in[4];
  float* out = (float*)d_out;

  unsigned short* ws      = (unsigned short*)d_ws;
  unsigned short* x_bf    = ws;                     //  8388608
  unsigned short* wqkv_t  = x_bf + 8388608;         //  3145728
  unsigned short* wo_t    = wqkv_t + 3145728;       //  1048576
  unsigned short* qkv     = wo_t + 1048576;         // 25165824 (3 x 2^23)
  unsigned short* attn_o  = qkv + 25165824;         //  8388608

  prep_fused<<<6144, 256, 0, stream>>>(x, x_bf, W_qkv, wqkv_t, W_o, wo_t);
  // GEMM1: 8192x3072, 128x128 tiles -> grid 24x64 = 1536 blocks
  gemm97<0><<<dim3(24, 64), 256, 0, stream>>>(x_bf, wqkv_t, b_qkv, qkv, nullptr);
  attn_mfma<<<1024, 512, 0, stream>>>(qkv, attn_o);
  // GEMM2: 8192x1024, 128x128 tiles -> grid 8x64 = 512 blocks
  gemm97<1><<<dim3(8, 64), 256, 0, stream>>>(attn_o, wo_t, b_o, nullptr, out);
}

// Round 17
// 153.434 us; speedup vs baseline: 1.1876x; 1.1876x over previous
//
#include <hip/hip_runtime.h>

// MHSA fwd MFMA bf16: B=8, N=1024, D=1024, H=16, DK=64. fp32 in/out, bf16 compute.
// Round 17: GEMM1 -> BM=128 BN=384 BK=32 in the R14 relaxed schedule (10 reads
// per 24 MFMA, grid 512 = 2 exact rounds, vmcnt(4)). GEMM2 = R14 128x256.
// Attention = R15 swapped-QK^T. prep unchanged.

typedef __attribute__((ext_vector_type(8))) short bf16x8;
typedef __attribute__((ext_vector_type(4))) float f32x4;

#define GLOAD_LDS16(gp, lp)                                                              \
  __builtin_amdgcn_global_load_lds((const __attribute__((address_space(1))) void*)(gp),  \
                                   (__attribute__((address_space(3))) void*)(lp), 16, 0, 0)

__device__ __forceinline__ unsigned short f2bf(float f) {
  unsigned int u = __float_as_uint(f);
  u += 0x7fffu + ((u >> 16) & 1u);          // RNE
  return (unsigned short)(u >> 16);
}

// ---------------------------------------------------------------------------
// Fused pre-pass: blocks [0,2048) cast x->bf16; [2048,5120) transpose W_qkv;
// [5120,6144) transpose W_o.
// ---------------------------------------------------------------------------
__global__ __launch_bounds__(256) void prep_fused(
    const float* __restrict__ x, unsigned short* __restrict__ x_bf,
    const float* __restrict__ W_qkv, unsigned short* __restrict__ wqkv_t,
    const float* __restrict__ W_o, unsigned short* __restrict__ wo_t) {
  const int b = blockIdx.x;
  if (b < 2048) {
    const int n4 = 8388608 / 4;
    for (int i = b * 256 + threadIdx.x; i < n4; i += 2048 * 256) {
      float4 v = reinterpret_cast<const float4*>(x)[i];
      ushort4 o;
      o.x = f2bf(v.x); o.y = f2bf(v.y); o.z = f2bf(v.z); o.w = f2bf(v.w);
      reinterpret_cast<ushort4*>(x_bf)[i] = o;
    }
  } else {
    __shared__ float tile[32][33];
    const float* W;
    unsigned short* Wt;
    int R = 1024, C, bx, by;
    if (b < 5120) {
      W = W_qkv; Wt = wqkv_t; C = 3072;
      int bb = b - 2048; bx = bb % 96; by = bb / 96;
    } else {
      W = W_o; Wt = wo_t; C = 1024;
      int bb = b - 5120; bx = bb & 31; by = bb >> 5;
    }
    const int tx = threadIdx.x & 31, ty = threadIdx.x >> 5;
    const int c0 = bx * 32, r0 = by * 32;
    #pragma unroll
    for (int i = 0; i < 4; i++) {
      int r = r0 + ty + i * 8;
      tile[ty + i * 8][tx] = W[(size_t)r * C + c0 + tx];
    }
    __syncthreads();
    #pragma unroll
    for (int i = 0; i < 4; i++) {
      int c = c0 + ty + i * 8;
      Wt[(size_t)c * R + r0 + tx] = f2bf(tile[tx][ty + i * 8]);
    }
  }
}

// ---------------------------------------------------------------------------
// GEMM1: 128x384, BK=32, 512 thr (8 waves = 2M x 4N; 64x96 per wave, 4x6
// frags). K=1024 -> 32 K-tiles. R14 relaxed schedule: 3-buf LDS (96 KB),
// stage kt+2 during kt, ONE tile-top vmcnt(4)+barrier+sched_barrier per tile.
// qkv scatter epilogue with per-frag `which` (384 straddles Q/K boundary).
// ---------------------------------------------------------------------------
__global__ __launch_bounds__(512) void gemm1_384(
    const unsigned short* __restrict__ A, const unsigned short* __restrict__ Bt,
    const float* __restrict__ bias, unsigned short* __restrict__ qkv_out) {
  __shared__ __align__(16) unsigned short As[3][128 * 32];   // 24 KB
  __shared__ __align__(16) unsigned short Bs[3][384 * 32];   // 72 KB
  const int t = threadIdx.x;
  const int lane = t & 63, wid = t >> 6;
  const int lr = lane & 15, g = lane >> 4;
  const int wm = wid >> 2, wn = wid & 3;

  // XCD swizzle (nwg = 512)
  const int nwg = gridDim.x * gridDim.y;
  const int id = blockIdx.x + gridDim.x * blockIdx.y;
  const int sw = (id & 7) * (nwg >> 3) + (id >> 3);
  const int bx = sw % gridDim.x, by = sw / gridDim.x;
  const int row0 = by * 128, col0 = bx * 384;

  const int srow = t >> 2;                       // 0..127 (64B rows: 32 bf16)
  const int sch  = (t & 3) ^ ((srow >> 1) & 3);  // source pre-swizzle chunk

  auto stA = [&](int buf, int kt) {
    GLOAD_LDS16(A + (size_t)(row0 + srow) * 1024 + kt * 32 + sch * 8,
                (char*)&As[buf][0] + t * 16);
  };
  auto stB = [&](int buf, int kt, int j) {   // j=0..2: rows j*128..j*128+127
    GLOAD_LDS16(Bt + (size_t)(col0 + j * 128 + srow) * 1024 + kt * 32 + sch * 8,
                (char*)&Bs[buf][0] + j * 8192 + t * 16);
  };
  auto rdA = [&](int buf, int m) -> bf16x8 {
    int r = wm * 64 + m * 16 + lr;
    return *(const bf16x8*)((const char*)&As[buf][0] + r * 64 +
                            ((g ^ ((r >> 1) & 3)) * 16));
  };
  auto rdB = [&](int buf, int n) -> bf16x8 {
    int r = wn * 96 + n * 16 + lr;
    return *(const bf16x8*)((const char*)&Bs[buf][0] + r * 64 +
                            ((g ^ ((r >> 1) & 3)) * 16));
  };

  f32x4 acc[4][6] = {};

  // prologue: stage tiles 0 and 1 (4 loads each)
  stA(0, 0); stB(0, 0, 0); stB(0, 0, 1); stB(0, 0, 2);
  stA(1, 1); stB(1, 1, 0); stB(1, 1, 1); stB(1, 1, 2);

  for (int kt = 0; kt < 32; kt++) {
    const int buf = kt % 3;
    const int bufn = (kt + 2) % 3;
    const bool pf = (kt <= 29);

    // tile-top: own 4 loads landed; kt+1's 4 stay in flight
    if (kt == 31) asm volatile("s_waitcnt vmcnt(0)" ::: "memory");
    else          asm volatile("s_waitcnt vmcnt(4)" ::: "memory");
    __builtin_amdgcn_s_barrier();
    __builtin_amdgcn_sched_barrier(0);   // staging below must not hoist above

    bf16x8 a[4], b[6];
    #pragma unroll
    for (int m = 0; m < 4; m++) a[m] = rdA(buf, m);
    #pragma unroll
    for (int n = 0; n < 6; n++) b[n] = rdB(buf, n);
    if (pf) { stA(bufn, kt + 2); stB(bufn, kt + 2, 0); stB(bufn, kt + 2, 1); stB(bufn, kt + 2, 2); }
    #pragma unroll
    for (int m = 0; m < 4; m++)
      #pragma unroll
      for (int n = 0; n < 6; n++)
        acc[m][n] = __builtin_amdgcn_mfma_f32_16x16x32_bf16(a[m], b[n], acc[m][n], 0, 0, 0);
  }

  // ---------------- epilogue: qkv scatter, per-frag which ----------------
  #pragma unroll
  for (int m = 0; m < 4; m++) {
    const int row = row0 + wm * 64 + m * 16 + g * 4;
    const int bb = row >> 10, nn = row & 1023;
    #pragma unroll
    for (int n = 0; n < 6; n++) {
      const int col = col0 + wn * 96 + n * 16 + lr;
      const int which = col >> 10;         // frag-uniform (16 | 1024)
      const int cc = col & 1023;
      const int h = cc >> 6, dk = cc & 63;
      const float bv = bias[col];
      if (which == 2) {
        ushort4 w;
        w.x = f2bf(acc[m][n][0] + bv);
        w.y = f2bf(acc[m][n][1] + bv);
        w.z = f2bf(acc[m][n][2] + bv);
        w.w = f2bf(acc[m][n][3] + bv);
        size_t idx = ((size_t)2 << 23) + (((size_t)(bb * 16 + h)) << 16) +
                     (size_t)dk * 1024 + nn;
        *(ushort4*)(qkv_out + idx) = w;
      } else {
        const float sc = (which == 0) ? 0.125f : 1.0f;
        #pragma unroll
        for (int r = 0; r < 4; r++) {
          size_t idx = ((size_t)which << 23) +
                       (((size_t)((bb * 16 + h) * 1024 + nn + r)) << 6) + dk;
          qkv_out[idx] = f2bf((acc[m][n][r] + bv) * sc);
        }
      }
    }
  }
}

// ---------------------------------------------------------------------------
// GEMM2 (R14 relaxed): 128x256, BK=64, 8 waves (2M x 4N, 64x64/wave), 3-buf,
// stage kt+2, tile-top vmcnt(6)+barrier+sched_barrier. f32 out + bias.
// ---------------------------------------------------------------------------
__global__ __launch_bounds__(512) void gemm2_k(
    const unsigned short* __restrict__ A, const unsigned short* __restrict__ Bt,
    const float* __restrict__ bias, float* __restrict__ Cout) {
  __shared__ __align__(16) unsigned short As[3][128 * 64];   // 48 KB
  __shared__ __align__(16) unsigned short Bs[3][256 * 64];   // 96 KB
  const int t = threadIdx.x;
  const int lane = t & 63, wid = t >> 6;
  const int lr = lane & 15, g = lane >> 4;
  const int wm = wid >> 2, wn = wid & 3;

  const int nwg = gridDim.x * gridDim.y;
  const int id = blockIdx.x + gridDim.x * blockIdx.y;
  const int sw = (id & 7) * (nwg >> 3) + (id >> 3);
  const int bx = sw % gridDim.x, by = sw / gridDim.x;
  const int row0 = by * 128, col0 = bx * 256;

  const int srow = t >> 3, sch = t & 7;     // 64 rows of 128B

  auto stA = [&](int buf, int kt, int j) {  // j=0..1
    int row = j * 64 + srow;
    int ch = sch ^ (row & 7);
    GLOAD_LDS16(A + (size_t)(row0 + row) * 1024 + kt * 64 + ch * 8,
                (char*)&As[buf][0] + j * 8192 + t * 16);
  };
  auto stB = [&](int buf, int kt, int j) {  // j=0..3
    int row = j * 64 + srow;
    int ch = sch ^ (row & 7);
    GLOAD_LDS16(Bt + (size_t)(col0 + row) * 1024 + kt * 64 + ch * 8,
                (char*)&Bs[buf][0] + j * 8192 + t * 16);
  };
  auto rdA = [&](int buf, int c, int m) -> bf16x8 {
    int r = wm * 64 + m * 16 + lr;
    return *(const bf16x8*)((const char*)&As[buf][0] + r * 128 +
                            ((c * 64 + g * 16) ^ ((r & 7) << 4)));
  };
  auto rdB = [&](int buf, int c, int n) -> bf16x8 {
    int r = wn * 64 + n * 16 + lr;
    return *(const bf16x8*)((const char*)&Bs[buf][0] + r * 128 +
                            ((c * 64 + g * 16) ^ ((r & 7) << 4)));
  };

  f32x4 acc[4][4] = {};

  stA(0, 0, 0); stA(0, 0, 1);
  stB(0, 0, 0); stB(0, 0, 1); stB(0, 0, 2); stB(0, 0, 3);
  stA(1, 1, 0); stA(1, 1, 1);
  stB(1, 1, 0); stB(1, 1, 1); stB(1, 1, 2); stB(1, 1, 3);

  for (int kt = 0; kt < 16; kt++) {
    const int buf = kt % 3;
    const int bufn = (kt + 2) % 3;
    const bool pf = (kt <= 13);

    if (kt == 15) asm volatile("s_waitcnt vmcnt(0)" ::: "memory");
    else          asm volatile("s_waitcnt vmcnt(6)" ::: "memory");
    __builtin_amdgcn_s_barrier();
    __builtin_amdgcn_sched_barrier(0);

    bf16x8 a0[4], b0[4];
    #pragma unroll
    for (int m = 0; m < 4; m++) a0[m] = rdA(buf, 0, m);
    #pragma unroll
    for (int n = 0; n < 4; n++) b0[n] = rdB(buf, 0, n);
    if (pf) { stA(bufn, kt + 2, 0); stA(bufn, kt + 2, 1); stB(bufn, kt + 2, 0); }
    #pragma unroll
    for (int m = 0; m < 4; m++)
      #pragma unroll
      for (int n = 0; n < 4; n++)
        acc[m][n] = __builtin_amdgcn_mfma_f32_16x16x32_bf16(a0[m], b0[n], acc[m][n], 0, 0, 0);

    bf16x8 a1[4], b1[4];
    #pragma unroll
    for (int m = 0; m < 4; m++) a1[m] = rdA(buf, 1, m);
    #pragma unroll
    for (int n = 0; n < 4; n++) b1[n] = rdB(buf, 1, n);
    if (pf) { stB(bufn, kt + 2, 1); stB(bufn, kt + 2, 2); stB(bufn, kt + 2, 3); }
    #pragma unroll
    for (int m = 0; m < 4; m++)
      #pragma unroll
      for (int n = 0; n < 4; n++)
        acc[m][n] = __builtin_amdgcn_mfma_f32_16x16x32_bf16(a1[m], b1[n], acc[m][n], 0, 0, 0);
  }

  #pragma unroll
  for (int m = 0; m < 4; m++) {
    #pragma unroll
    for (int n = 0; n < 4; n++) {
      int col = col0 + wn * 64 + n * 16 + lr;
      #pragma unroll
      for (int r = 0; r < 4; r++) {
        int row = row0 + wm * 64 + m * 16 + g * 4 + r;
        Cout[(size_t)row * 1024 + col] = acc[m][n][r] + bias[col];
      }
    }
  }
}

// ---------------------------------------------------------------------------
// Attention v7 (R15): 8 waves, QBLK=128, KVBLK=64, dbuf K+V via swizzled
// global_load_lds. Swapped QK^T (s4 = mfma(K,Q)): lane holds P[q=lr][4
// consecutive k] -> packed ds_write_b64; den scalar per lane, reduced at end.
// ---------------------------------------------------------------------------
__global__ __launch_bounds__(512) void attn_mfma(
    const unsigned short* __restrict__ qkv, unsigned short* __restrict__ attn_out) {
  __shared__ __align__(16) unsigned short K_lds[2][64 * 64];   // [k][d] swz
  __shared__ __align__(16) unsigned short V_lds[2][64 * 64];   // [d][k] swz
  __shared__ __align__(16) unsigned short P_lds[128 * 64];     // [q][k] swz

  const int bid = ((blockIdx.x & 7) << 7) + (blockIdx.x >> 3);
  const int bh = bid >> 3, qt = bid & 7;
  const unsigned short* Qp = qkv + ((size_t)bh << 16);
  const unsigned short* Kp = qkv + (1u << 23) + ((size_t)bh << 16);
  const unsigned short* Vt = qkv + (2u << 23) + ((size_t)bh << 16);  // [dk][n]

  const int t = threadIdx.x;
  const int lane = t & 63, wid = t >> 6;
  const int lr = lane & 15, g = lane >> 4;

  bf16x8 qf[2];
  {
    int qrow = qt * 128 + wid * 16 + lr;
    qf[0] = *(const bf16x8*)(Qp + (size_t)qrow * 64 + g * 8);
    qf[1] = *(const bf16x8*)(Qp + (size_t)qrow * 64 + 32 + g * 8);
  }

  const int srow = t >> 3;
  const int sch  = (t & 7) ^ (srow & 7);
  const int so   = t * 16;

  auto stage = [&](int buf, int kt) {
    GLOAD_LDS16(Kp + (size_t)(kt * 64 + srow) * 64 + sch * 8, (char*)&K_lds[buf][0] + so);
    GLOAD_LDS16(Vt + (size_t)srow * 1024 + kt * 64 + sch * 8, (char*)&V_lds[buf][0] + so);
  };

  f32x4 o_acc[4] = {};
  float den_l = 0.f;
  const int qrow_w = wid * 16 + lr;

  stage(0, 0);
  __syncthreads();
  int buf = 0;
  for (int kt = 0; kt < 16; kt++) {
    if (kt + 1 < 16) stage(buf ^ 1, kt + 1);

    f32x4 s4[4] = {};
    __builtin_amdgcn_s_setprio(1);
    #pragma unroll
    for (int ks = 0; ks < 4; ks++) {
      int krow = ks * 16 + lr;
      #pragma unroll
      for (int c = 0; c < 2; c++) {
        bf16x8 kf = *(const bf16x8*)((char*)&K_lds[buf][0] + krow * 128 +
                                     ((c * 64 + g * 16) ^ ((krow & 7) << 4)));
        s4[ks] = __builtin_amdgcn_mfma_f32_16x16x32_bf16(kf, qf[c], s4[ks], 0, 0, 0);
      }
    }
    __builtin_amdgcn_s_setprio(0);

    #pragma unroll
    for (int ks = 0; ks < 4; ks++) {
      float e0 = __expf(s4[ks][0]);
      float e1 = __expf(s4[ks][1]);
      float e2 = __expf(s4[ks][2]);
      float e3 = __expf(s4[ks][3]);
      den_l += (e0 + e1) + (e2 + e3);
      unsigned int lo = (unsigned int)f2bf(e0) | ((unsigned int)f2bf(e1) << 16);
      unsigned int hi = (unsigned int)f2bf(e2) | ((unsigned int)f2bf(e3) << 16);
      int k0 = ks * 16 + g * 4;
      *(uint2*)((char*)P_lds + qrow_w * 128 +
                ((k0 * 2) ^ ((qrow_w & 7) << 4))) = make_uint2(lo, hi);
    }

    bf16x8 pa[2];
    {
      int q = wid * 16 + lr;
      #pragma unroll
      for (int c = 0; c < 2; c++)
        pa[c] = *(const bf16x8*)((char*)P_lds + q * 128 +
                                 ((c * 64 + g * 16) ^ ((q & 7) << 4)));
    }
    __builtin_amdgcn_s_setprio(1);
    #pragma unroll
    for (int ds_ = 0; ds_ < 4; ds_++) {
      int drow = ds_ * 16 + lr;
      #pragma unroll
      for (int c = 0; c < 2; c++) {
        bf16x8 vf = *(const bf16x8*)((char*)&V_lds[buf][0] + drow * 128 +
                                     ((c * 64 + g * 16) ^ ((drow & 7) << 4)));
        o_acc[ds_] = __builtin_amdgcn_mfma_f32_16x16x32_bf16(pa[c], vf, o_acc[ds_], 0, 0, 0);
      }
    }
    __builtin_amdgcn_s_setprio(0);
    __syncthreads();
    buf ^= 1;
  }

  den_l += __shfl_xor(den_l, 16, 64);
  den_l += __shfl_xor(den_l, 32, 64);
  float den_r[4];
  #pragma unroll
  for (int r = 0; r < 4; r++) den_r[r] = __shfl(den_l, g * 4 + r, 64);

  const int bb = bh >> 4, h = bh & 15;
  #pragma unroll
  for (int ds_ = 0; ds_ < 4; ds_++) {
    #pragma unroll
    for (int r = 0; r < 4; r++) {
      int q = qt * 128 + wid * 16 + g * 4 + r;
      int d = h * 64 + ds_ * 16 + lr;
      attn_out[((size_t)(bb * 1024 + q)) * 1024 + d] = f2bf(o_acc[ds_][r] / den_r[r]);
    }
  }
}

// ---------------------------------------------------------------------------
extern "C" void kernel_launch(void* const* d_in, const int* in_sizes, int n_in,
                              void* d_out, int out_size, void* d_ws, size_t ws_size,
                              hipStream_t stream) {
  const float* x     = (const float*)d_in[0];
  const float* W_qkv = (const float*)d_in[1];
  const float* b_qkv = (const float*)d_in[2];
  const float* W_o   = (const float*)d_in[3];
  const float* b_o   = (const float*)d_in[4];
  float* out = (float*)d_out;

  unsigned short* ws      = (unsigned short*)d_ws;
  unsigned short* x_bf    = ws;                     //  8388608
  unsigned short* wqkv_t  = x_bf + 8388608;         //  3145728
  unsigned short* wo_t    = wqkv_t + 3145728;       //  1048576
  unsigned short* qkv     = wo_t + 1048576;         // 25165824 (3 x 2^23)
  unsigned short* attn_o  = qkv + 25165824;         //  8388608

  prep_fused<<<6144, 256, 0, stream>>>(x, x_bf, W_qkv, wqkv_t, W_o, wo_t);
  // GEMM1: 8192x3072, 128x384 tiles -> grid 8x64 = 512 blocks (2 exact rounds)
  gemm1_384<<<dim3(8, 64), 512, 0, stream>>>(x_bf, wqkv_t, b_qkv, qkv);
  attn_mfma<<<1024, 512, 0, stream>>>(qkv, attn_o);
  // GEMM2: 8192x1024, 128x256 tiles -> grid 4x64 = 256 blocks (1 exact round)
  gemm2_k<<<dim3(4, 64), 512, 0, stream>>>(attn_o, wo_t, b_o, out);
}